// Round 1
// baseline (933.241 us; speedup 1.0000x reference)
//
#include <hip/hip_runtime.h>
#include <math.h>

#define S_LEN 4096
#define HIDDEN 2048
#define N_HEADS 16
#define N_KV 4
#define HEAD_DIM 128
#define QDIM 2048
#define KDIM 512
#define QKVD 3072
#define ATTN_SCALE 0.08838834764831845f

typedef __bf16 bf16x8 __attribute__((ext_vector_type(8)));
typedef float f32x4 __attribute__((ext_vector_type(4)));

__device__ __forceinline__ unsigned short f2bf(float x) {
  union { float f; unsigned u; } v; v.f = x;
  unsigned r = v.u + 0x7fffu + ((v.u >> 16) & 1u);
  return (unsigned short)(r >> 16);
}

__device__ __forceinline__ float wave_sum(float x) {
#pragma unroll
  for (int w = 32; w >= 1; w >>= 1) x += __shfl_xor(x, w);
  return x;
}

// ---------------- f32 -> bf16 convert (n4 = n/4) ----------------
__global__ void k_cvt(const float* __restrict__ s, unsigned short* __restrict__ d, int n4) {
  int i = blockIdx.x * blockDim.x + threadIdx.x;
  if (i >= n4) return;
  float4 v = reinterpret_cast<const float4*>(s)[i];
  ushort4 o;
  o.x = f2bf(v.x); o.y = f2bf(v.y); o.z = f2bf(v.z); o.w = f2bf(v.w);
  reinterpret_cast<ushort4*>(d)[i] = o;
}

// ---------------- RoPE cos/sin table [S][64] ----------------
__global__ void k_rope_tab(float* __restrict__ cosT, float* __restrict__ sinT) {
  int idx = blockIdx.x * blockDim.x + threadIdx.x;  // S*64
  int s = idx >> 6, d = idx & 63;
  float inv = powf(10000.0f, -(float)(2 * d) * (1.0f / 128.0f));
  float f = (float)s * inv;
  cosT[idx] = cosf(f);
  sinT[idx] = sinf(f);
}

// ---------------- GEMM: C[M,N] = A[M,K] * B[N,K]^T  (bf16 in, f32 out) ----------------
#define BM 128
#define BN 128
#define BK 32

__global__ __launch_bounds__(256) void k_gemm_bt(
    const unsigned short* __restrict__ A, const unsigned short* __restrict__ B,
    float* __restrict__ C, int M, int N, int K) {
  __shared__ unsigned short lds[2][BM * BK + BN * BK];
  const int tid = threadIdx.x;
  const int wave = tid >> 6, lane = tid & 63;
  const int brow = blockIdx.y * BM, bcol = blockIdx.x * BN;
  const int wr = wave >> 1, wc = wave & 1;
  const unsigned short* Ab = A + (size_t)brow * K;
  const unsigned short* Bb = B + (size_t)bcol * K;
  const int r0 = tid >> 2;       // 0..63
  const int c0 = (tid & 3) * 8;  // element col offset within BK

  f32x4 acc[4][4] = {};

  // prologue: stage buffer 0, k-tile 0
#pragma unroll
  for (int c = 0; c < 2; ++c) {
    __builtin_amdgcn_global_load_lds(
        (const __attribute__((address_space(1))) void*)(Ab + (size_t)(c * 64 + r0) * K + c0),
        (__attribute__((address_space(3))) void*)(&lds[0][(c * 64 + r0) * BK + c0]), 16, 0, 0);
    __builtin_amdgcn_global_load_lds(
        (const __attribute__((address_space(1))) void*)(Bb + (size_t)(c * 64 + r0) * K + c0),
        (__attribute__((address_space(3))) void*)(&lds[0][BM * BK + (c * 64 + r0) * BK + c0]), 16, 0, 0);
  }

  const int KT = K / BK;
  const int arow = wr * 64 + (lane & 15);
  const int brow2 = wc * 64 + (lane & 15);
  const int koff = (lane >> 4) * 8;

  for (int kt = 0; kt < KT; ++kt) {
    if (kt + 1 < KT) {
      const int k0 = (kt + 1) * BK;
      const int buf = (kt + 1) & 1;
#pragma unroll
      for (int c = 0; c < 2; ++c) {
        __builtin_amdgcn_global_load_lds(
            (const __attribute__((address_space(1))) void*)(Ab + (size_t)(c * 64 + r0) * K + k0 + c0),
            (__attribute__((address_space(3))) void*)(&lds[buf][(c * 64 + r0) * BK + c0]), 16, 0, 0);
        __builtin_amdgcn_global_load_lds(
            (const __attribute__((address_space(1))) void*)(Bb + (size_t)(c * 64 + r0) * K + k0 + c0),
            (__attribute__((address_space(3))) void*)(&lds[buf][BM * BK + (c * 64 + r0) * BK + c0]), 16, 0, 0);
      }
    }
    __syncthreads();
    const unsigned short* la = &lds[kt & 1][0];
    const unsigned short* lb = &lds[kt & 1][BM * BK];
    bf16x8 a[4], b[4];
#pragma unroll
    for (int m = 0; m < 4; ++m)
      a[m] = *reinterpret_cast<const bf16x8*>(la + (arow + m * 16) * BK + koff);
#pragma unroll
    for (int n = 0; n < 4; ++n)
      b[n] = *reinterpret_cast<const bf16x8*>(lb + (brow2 + n * 16) * BK + koff);
#pragma unroll
    for (int m = 0; m < 4; ++m)
#pragma unroll
      for (int n = 0; n < 4; ++n)
        acc[m][n] = __builtin_amdgcn_mfma_f32_16x16x32_bf16(a[m], b[n], acc[m][n], 0, 0, 0);
    __syncthreads();
  }

  const int crow = brow + wr * 64 + (lane >> 4) * 4;
  const int ccol = bcol + wc * 64 + (lane & 15);
#pragma unroll
  for (int m = 0; m < 4; ++m)
#pragma unroll
    for (int n = 0; n < 4; ++n)
#pragma unroll
      for (int i = 0; i < 4; ++i)
        C[(size_t)(crow + m * 16 + i) * N + ccol + n * 16] = acc[m][n][i];
}

// ---------------- RMSNorm + RoPE + layout ----------------
// QKV row: [q 2048][k 512][v 512] f32. Writes Q[NH][S][HD], K[NKV][S][HD], Vt[NKV][HD][S] bf16.
__global__ __launch_bounds__(256) void k_norm_rope(
    const float* __restrict__ QKV, const float* __restrict__ qw, const float* __restrict__ kw,
    const float* __restrict__ cosT, const float* __restrict__ sinT,
    unsigned short* __restrict__ Q, unsigned short* __restrict__ Kd, unsigned short* __restrict__ Vt) {
  const int s = blockIdx.x;
  const int tid = threadIdx.x;
  const int lane = tid & 63, wave = tid >> 6;
  const float* row = QKV + (size_t)s * QKVD;
  __shared__ float sm[QDIM];
  __shared__ float red[4];

  // ---- Q (2048, 8 per thread) ----
  float qv[8];
  *reinterpret_cast<float4*>(&qv[0]) = reinterpret_cast<const float4*>(row)[tid * 2];
  *reinterpret_cast<float4*>(&qv[4]) = reinterpret_cast<const float4*>(row)[tid * 2 + 1];
  float ss = 0;
#pragma unroll
  for (int j = 0; j < 8; ++j) ss += qv[j] * qv[j];
  ss = wave_sum(ss);
  if (lane == 0) red[wave] = ss;
  __syncthreads();
  float tot = red[0] + red[1] + red[2] + red[3];
  float qs = rsqrtf(tot * (1.0f / QDIM) + 1e-5f) * ATTN_SCALE;
#pragma unroll
  for (int j = 0; j < 8; ++j) sm[tid * 8 + j] = qv[j] * qs * qw[tid * 8 + j];
  __syncthreads();
  {
    const int d0 = tid * 8;
    const int h = d0 >> 7;
    const int dh = d0 & 127;
    const int dc = dh & 63;
    const bool lo = dh < 64;
    const float sgn = lo ? -1.0f : 1.0f;
    const int po = lo ? 64 : -64;
    union { unsigned short b[8]; uint4 u; } pk;
#pragma unroll
    for (int j = 0; j < 8; ++j) {
      float c = cosT[s * 64 + dc + j];
      float sn = sinT[s * 64 + dc + j];
      float o = sm[d0 + j] * c + sgn * sm[d0 + po + j] * sn;
      pk.b[j] = f2bf(o);
    }
    *reinterpret_cast<uint4*>(Q + ((size_t)h * S_LEN + s) * HEAD_DIM + dh) = pk.u;
  }
  __syncthreads();

  // ---- K (512, 2 per thread) ----
  float2 kvp = *reinterpret_cast<const float2*>(row + QDIM + tid * 2);
  ss = kvp.x * kvp.x + kvp.y * kvp.y;
  ss = wave_sum(ss);
  if (lane == 0) red[wave] = ss;
  __syncthreads();
  tot = red[0] + red[1] + red[2] + red[3];
  float ks = rsqrtf(tot * (1.0f / KDIM) + 1e-5f);
  sm[tid * 2] = kvp.x * ks * kw[tid * 2];
  sm[tid * 2 + 1] = kvp.y * ks * kw[tid * 2 + 1];
  __syncthreads();
  {
    const int d0 = tid * 2;
    const int g = d0 >> 7;
    const int dh = d0 & 127;
    const int dc = dh & 63;
    const bool lo = dh < 64;
    const float sgn = lo ? -1.0f : 1.0f;
    const int po = lo ? 64 : -64;
    union { unsigned short b[2]; unsigned u; } pk;
#pragma unroll
    for (int j = 0; j < 2; ++j) {
      float c = cosT[s * 64 + dc + j];
      float sn = sinT[s * 64 + dc + j];
      float o = sm[d0 + j] * c + sgn * sm[d0 + po + j] * sn;
      pk.b[j] = f2bf(o);
    }
    *reinterpret_cast<unsigned*>(Kd + ((size_t)g * S_LEN + s) * HEAD_DIM + dh) = pk.u;
  }

  // ---- V (512, transposed store Vt[g][d][s]) ----
  {
    float2 vv = *reinterpret_cast<const float2*>(row + QDIM + KDIM + tid * 2);
    int dv = tid * 2;
    int g = dv >> 7, d = dv & 127;
    Vt[(size_t)(g * HEAD_DIM + d) * S_LEN + s] = f2bf(vv.x);
    Vt[(size_t)(g * HEAD_DIM + d + 1) * S_LEN + s] = f2bf(vv.y);
  }
}

// ---------------- Causal GQA flash attention ----------------
// Q[NH][S][HD], K[NKV][S][HD], Vt[NKV][HD][S] bf16 -> AO[S][NH*HD] bf16.
// 4 waves/block, each wave owns 16 q rows; KV tiles of 32.
__global__ __launch_bounds__(256) void k_attn(
    const unsigned short* __restrict__ Q, const unsigned short* __restrict__ K,
    const unsigned short* __restrict__ Vt, unsigned short* __restrict__ AO) {
  const int h = blockIdx.y;
  const int g = h >> 2;
  const int wave = threadIdx.x >> 6, lane = threadIdx.x & 63;
  const int q0 = blockIdx.x * 64 + wave * 16;
  const unsigned short* Qh = Q + ((size_t)h * S_LEN + q0) * HEAD_DIM;
  const unsigned short* Kg = K + (size_t)g * S_LEN * HEAD_DIM;
  const unsigned short* Vg = Vt + (size_t)g * HEAD_DIM * S_LEN;

  const int l15 = lane & 15;
  const int koff = (lane >> 4) * 8;

  bf16x8 aq[4];
#pragma unroll
  for (int dt = 0; dt < 4; ++dt)
    aq[dt] = *reinterpret_cast<const bf16x8*>(Qh + (size_t)l15 * HEAD_DIM + dt * 32 + koff);

  f32x4 o[8] = {};
  float m[4] = {-1e30f, -1e30f, -1e30f, -1e30f};
  float l[4] = {0, 0, 0, 0};

  __shared__ unsigned short plds[4][16 * 32];
  unsigned short* pw = plds[wave];

  const int kv_end = q0 + 16;
  for (int kv = 0; kv < kv_end; kv += 32) {
    f32x4 sc[2];
#pragma unroll
    for (int kb = 0; kb < 2; ++kb) {
      f32x4 z = {0.f, 0.f, 0.f, 0.f};
      sc[kb] = z;
      const unsigned short* Kp = Kg + (size_t)(kv + kb * 16 + l15) * HEAD_DIM + koff;
#pragma unroll
      for (int dt = 0; dt < 4; ++dt) {
        bf16x8 bk = *reinterpret_cast<const bf16x8*>(Kp + dt * 32);
        sc[kb] = __builtin_amdgcn_mfma_f32_16x16x32_bf16(aq[dt], bk, sc[kb], 0, 0, 0);
      }
    }
    if (kv + 32 > q0) {  // diagonal tile: elementwise causal mask
#pragma unroll
      for (int kb = 0; kb < 2; ++kb) {
        int kvc = kv + kb * 16 + l15;
#pragma unroll
        for (int i = 0; i < 4; ++i)
          if (kvc > q0 + (lane >> 4) * 4 + i) sc[kb][i] = -1e30f;
      }
    }
    float pm[4];
#pragma unroll
    for (int i = 0; i < 4; ++i) pm[i] = fmaxf(sc[0][i], sc[1][i]);
#pragma unroll
    for (int w = 8; w >= 1; w >>= 1)
#pragma unroll
      for (int i = 0; i < 4; ++i) pm[i] = fmaxf(pm[i], __shfl_xor(pm[i], w));

    float fac[4], rs[4], p[2][4];
#pragma unroll
    for (int i = 0; i < 4; ++i) {
      float mn = fmaxf(m[i], pm[i]);
      fac[i] = exp2f((m[i] - mn) * 1.44269504f);
      m[i] = mn;
      p[0][i] = exp2f((sc[0][i] - mn) * 1.44269504f);
      p[1][i] = exp2f((sc[1][i] - mn) * 1.44269504f);
      rs[i] = p[0][i] + p[1][i];
    }
#pragma unroll
    for (int w = 8; w >= 1; w >>= 1)
#pragma unroll
      for (int i = 0; i < 4; ++i) rs[i] += __shfl_xor(rs[i], w);
#pragma unroll
    for (int i = 0; i < 4; ++i) l[i] = l[i] * fac[i] + rs[i];
#pragma unroll
    for (int db = 0; db < 8; ++db)
#pragma unroll
      for (int i = 0; i < 4; ++i) o[db][i] *= fac[i];

    // P (D-layout) -> LDS -> A-fragment layout
#pragma unroll
    for (int kb = 0; kb < 2; ++kb)
#pragma unroll
      for (int i = 0; i < 4; ++i)
        pw[((lane >> 4) * 4 + i) * 32 + kb * 16 + l15] = f2bf(p[kb][i]);
    asm volatile("s_waitcnt lgkmcnt(0)" ::: "memory");
    bf16x8 pa = *reinterpret_cast<const bf16x8*>(pw + l15 * 32 + koff);
#pragma unroll
    for (int db = 0; db < 8; ++db) {
      bf16x8 bv = *reinterpret_cast<const bf16x8*>(Vg + (size_t)(db * 16 + l15) * S_LEN + kv + koff);
      o[db] = __builtin_amdgcn_mfma_f32_16x16x32_bf16(pa, bv, o[db], 0, 0, 0);
    }
  }

#pragma unroll
  for (int i = 0; i < 4; ++i) {
    float inv = 1.0f / l[i];
    int srow = q0 + (lane >> 4) * 4 + i;
#pragma unroll
    for (int db = 0; db < 8; ++db)
      AO[(size_t)srow * QDIM + h * HEAD_DIM + db * 16 + l15] = f2bf(o[db][i] * inv);
  }
}

extern "C" void kernel_launch(void* const* d_in, const int* in_sizes, int n_in,
                              void* d_out, int out_size, void* d_ws, size_t ws_size,
                              hipStream_t stream) {
  const float* hs = (const float*)d_in[0];
  const float* wq = (const float*)d_in[1];
  const float* wk = (const float*)d_in[2];
  const float* wv = (const float*)d_in[3];
  const float* wo = (const float*)d_in[4];
  const float* qnw = (const float*)d_in[5];
  const float* knw = (const float*)d_in[6];
  float* out = (float*)d_out;

  // workspace layout (regions reused across pipeline stages):
  char* base = (char*)d_ws;
  unsigned short* Xb = (unsigned short*)base;              // 16.78 MB (dead after GEMM1)
  unsigned short* Qb = Xb;                                 // reuse
  unsigned short* Wqkv = (unsigned short*)(base + 16777216);  // 12.58 MB (dead after GEMM1)
  unsigned short* Kb = Wqkv;                               // reuse (4.19 MB)
  unsigned short* Vtb = (unsigned short*)(base + 16777216 + 4194304);  // reuse (4.19 MB)
  unsigned short* Wob = (unsigned short*)(base + 29360128);  // 8.39 MB (live to end)
  float* QKV = (float*)(base + 37748736);                  // 50.33 MB (dead after norm_rope)
  unsigned short* AOb = (unsigned short*)QKV;              // reuse (16.78 MB)
  float* cosT = (float*)(base + 88080384);                 // 1 MB
  float* sinT = (float*)(base + 89128960);                 // 1 MB

  int n;
  n = S_LEN * HIDDEN / 4; k_cvt<<<(n + 255) / 256, 256, 0, stream>>>(hs, Xb, n);
  n = QDIM * HIDDEN / 4;  k_cvt<<<(n + 255) / 256, 256, 0, stream>>>(wq, Wqkv, n);
  n = KDIM * HIDDEN / 4;  k_cvt<<<(n + 255) / 256, 256, 0, stream>>>(wk, Wqkv + (size_t)QDIM * HIDDEN, n);
  n = KDIM * HIDDEN / 4;  k_cvt<<<(n + 255) / 256, 256, 0, stream>>>(wv, Wqkv + (size_t)(QDIM + KDIM) * HIDDEN, n);
  n = HIDDEN * QDIM / 4;  k_cvt<<<(n + 255) / 256, 256, 0, stream>>>(wo, Wob, n);
  k_rope_tab<<<(S_LEN * 64) / 256, 256, 0, stream>>>(cosT, sinT);

  k_gemm_bt<<<dim3(QKVD / BN, S_LEN / BM), 256, 0, stream>>>(Xb, Wqkv, QKV, S_LEN, QKVD, HIDDEN);
  k_norm_rope<<<S_LEN, 256, 0, stream>>>(QKV, qnw, knw, cosT, sinT, Qb, Kb, Vtb);
  k_attn<<<dim3(S_LEN / 64, N_HEADS), 256, 0, stream>>>(Qb, Kb, Vtb, AOb);
  k_gemm_bt<<<dim3(QDIM / BN, S_LEN / BM), 256, 0, stream>>>(AOb, Wob, out, S_LEN, QDIM, HIDDEN);
}

// Round 2
// 746.990 us; speedup vs baseline: 1.2493x; 1.2493x over previous
//
#include <hip/hip_runtime.h>
#include <math.h>

#define S_LEN 4096
#define HIDDEN 2048
#define N_HEADS 16
#define N_KV 4
#define HEAD_DIM 128
#define QDIM 2048
#define KDIM 512
#define QKVD 3072
#define ATTN_SCALE 0.08838834764831845f

typedef __bf16 bf16x8 __attribute__((ext_vector_type(8)));
typedef float f32x4 __attribute__((ext_vector_type(4)));

__device__ __forceinline__ unsigned short f2bf(float x) {
  union { float f; unsigned u; } v; v.f = x;
  unsigned r = v.u + 0x7fffu + ((v.u >> 16) & 1u);
  return (unsigned short)(r >> 16);
}

__device__ __forceinline__ float wave_sum(float x) {
#pragma unroll
  for (int w = 32; w >= 1; w >>= 1) x += __shfl_xor(x, w);
  return x;
}

// ---------------- f32 -> bf16 convert (n4 = n/4) ----------------
__global__ void k_cvt(const float* __restrict__ s, unsigned short* __restrict__ d, int n4) {
  int i = blockIdx.x * blockDim.x + threadIdx.x;
  if (i >= n4) return;
  float4 v = reinterpret_cast<const float4*>(s)[i];
  ushort4 o;
  o.x = f2bf(v.x); o.y = f2bf(v.y); o.z = f2bf(v.z); o.w = f2bf(v.w);
  reinterpret_cast<ushort4*>(d)[i] = o;
}

// ---------------- RoPE cos/sin table [S][64] ----------------
__global__ void k_rope_tab(float* __restrict__ cosT, float* __restrict__ sinT) {
  int idx = blockIdx.x * blockDim.x + threadIdx.x;  // S*64
  int s = idx >> 6, d = idx & 63;
  float inv = powf(10000.0f, -(float)(2 * d) * (1.0f / 128.0f));
  float f = (float)s * inv;
  cosT[idx] = cosf(f);
  sinT[idx] = sinf(f);
}

// ---------------- GEMM: C[M,N] = A[M,K] * B[N,K]^T  (bf16 in, f32 out) ----------------
#define BM 128
#define BN 128
#define BK 32

__global__ __launch_bounds__(256) void k_gemm_bt(
    const unsigned short* __restrict__ A, const unsigned short* __restrict__ B,
    float* __restrict__ C, int M, int N, int K) {
  __shared__ unsigned short lds[2][BM * BK + BN * BK];
  const int tid = threadIdx.x;
  const int wave = tid >> 6, lane = tid & 63;
  const int brow = blockIdx.y * BM, bcol = blockIdx.x * BN;
  const int wr = wave >> 1, wc = wave & 1;
  const unsigned short* Ab = A + (size_t)brow * K;
  const unsigned short* Bb = B + (size_t)bcol * K;
  const int r0 = tid >> 2;       // 0..63
  const int c0 = (tid & 3) * 8;  // element col offset within BK

  f32x4 acc[4][4] = {};

#pragma unroll
  for (int c = 0; c < 2; ++c) {
    __builtin_amdgcn_global_load_lds(
        (const __attribute__((address_space(1))) void*)(Ab + (size_t)(c * 64 + r0) * K + c0),
        (__attribute__((address_space(3))) void*)(&lds[0][(c * 64 + r0) * BK + c0]), 16, 0, 0);
    __builtin_amdgcn_global_load_lds(
        (const __attribute__((address_space(1))) void*)(Bb + (size_t)(c * 64 + r0) * K + c0),
        (__attribute__((address_space(3))) void*)(&lds[0][BM * BK + (c * 64 + r0) * BK + c0]), 16, 0, 0);
  }

  const int KT = K / BK;
  const int arow = wr * 64 + (lane & 15);
  const int brow2 = wc * 64 + (lane & 15);
  const int koff = (lane >> 4) * 8;

  for (int kt = 0; kt < KT; ++kt) {
    if (kt + 1 < KT) {
      const int k0 = (kt + 1) * BK;
      const int buf = (kt + 1) & 1;
#pragma unroll
      for (int c = 0; c < 2; ++c) {
        __builtin_amdgcn_global_load_lds(
            (const __attribute__((address_space(1))) void*)(Ab + (size_t)(c * 64 + r0) * K + k0 + c0),
            (__attribute__((address_space(3))) void*)(&lds[buf][(c * 64 + r0) * BK + c0]), 16, 0, 0);
        __builtin_amdgcn_global_load_lds(
            (const __attribute__((address_space(1))) void*)(Bb + (size_t)(c * 64 + r0) * K + k0 + c0),
            (__attribute__((address_space(3))) void*)(&lds[buf][BM * BK + (c * 64 + r0) * BK + c0]), 16, 0, 0);
      }
    }
    __syncthreads();
    const unsigned short* la = &lds[kt & 1][0];
    const unsigned short* lb = &lds[kt & 1][BM * BK];
    bf16x8 a[4], b[4];
#pragma unroll
    for (int m = 0; m < 4; ++m)
      a[m] = *reinterpret_cast<const bf16x8*>(la + (arow + m * 16) * BK + koff);
#pragma unroll
    for (int n = 0; n < 4; ++n)
      b[n] = *reinterpret_cast<const bf16x8*>(lb + (brow2 + n * 16) * BK + koff);
#pragma unroll
    for (int m = 0; m < 4; ++m)
#pragma unroll
      for (int n = 0; n < 4; ++n)
        acc[m][n] = __builtin_amdgcn_mfma_f32_16x16x32_bf16(a[m], b[n], acc[m][n], 0, 0, 0);
    __syncthreads();
  }

  const int crow = brow + wr * 64 + (lane >> 4) * 4;
  const int ccol = bcol + wc * 64 + (lane & 15);
#pragma unroll
  for (int m = 0; m < 4; ++m)
#pragma unroll
    for (int n = 0; n < 4; ++n)
#pragma unroll
      for (int i = 0; i < 4; ++i)
        C[(size_t)(crow + m * 16 + i) * N + ccol + n * 16] = acc[m][n][i];
}

// ---------------- RMSNorm + RoPE + layout ----------------
__global__ __launch_bounds__(256) void k_norm_rope(
    const float* __restrict__ QKV, const float* __restrict__ qw, const float* __restrict__ kw,
    const float* __restrict__ cosT, const float* __restrict__ sinT,
    unsigned short* __restrict__ Q, unsigned short* __restrict__ Kd, unsigned short* __restrict__ Vt) {
  const int s = blockIdx.x;
  const int tid = threadIdx.x;
  const int lane = tid & 63, wave = tid >> 6;
  const float* row = QKV + (size_t)s * QKVD;
  __shared__ float sm[QDIM];
  __shared__ float red[4];

  // ---- Q (2048, 8 per thread) ----
  float qv[8];
  *reinterpret_cast<float4*>(&qv[0]) = reinterpret_cast<const float4*>(row)[tid * 2];
  *reinterpret_cast<float4*>(&qv[4]) = reinterpret_cast<const float4*>(row)[tid * 2 + 1];
  float ss = 0;
#pragma unroll
  for (int j = 0; j < 8; ++j) ss += qv[j] * qv[j];
  ss = wave_sum(ss);
  if (lane == 0) red[wave] = ss;
  __syncthreads();
  float tot = red[0] + red[1] + red[2] + red[3];
  float qs = rsqrtf(tot * (1.0f / QDIM) + 1e-5f) * ATTN_SCALE;
#pragma unroll
  for (int j = 0; j < 8; ++j) sm[tid * 8 + j] = qv[j] * qs * qw[tid * 8 + j];
  __syncthreads();
  {
    const int d0 = tid * 8;
    const int h = d0 >> 7;
    const int dh = d0 & 127;
    const int dc = dh & 63;
    const bool lo = dh < 64;
    const float sgn = lo ? -1.0f : 1.0f;
    const int po = lo ? 64 : -64;
    union { unsigned short b[8]; uint4 u; } pk;
#pragma unroll
    for (int j = 0; j < 8; ++j) {
      float c = cosT[s * 64 + dc + j];
      float sn = sinT[s * 64 + dc + j];
      float o = sm[d0 + j] * c + sgn * sm[d0 + po + j] * sn;
      pk.b[j] = f2bf(o);
    }
    *reinterpret_cast<uint4*>(Q + ((size_t)h * S_LEN + s) * HEAD_DIM + dh) = pk.u;
  }
  __syncthreads();

  // ---- K (512, 2 per thread) ----
  float2 kvp = *reinterpret_cast<const float2*>(row + QDIM + tid * 2);
  ss = kvp.x * kvp.x + kvp.y * kvp.y;
  ss = wave_sum(ss);
  if (lane == 0) red[wave] = ss;
  __syncthreads();
  tot = red[0] + red[1] + red[2] + red[3];
  float ks = rsqrtf(tot * (1.0f / KDIM) + 1e-5f);
  sm[tid * 2] = kvp.x * ks * kw[tid * 2];
  sm[tid * 2 + 1] = kvp.y * ks * kw[tid * 2 + 1];
  __syncthreads();
  {
    const int d0 = tid * 2;
    const int g = d0 >> 7;
    const int dh = d0 & 127;
    const int dc = dh & 63;
    const bool lo = dh < 64;
    const float sgn = lo ? -1.0f : 1.0f;
    const int po = lo ? 64 : -64;
    union { unsigned short b[2]; unsigned u; } pk;
#pragma unroll
    for (int j = 0; j < 2; ++j) {
      float c = cosT[s * 64 + dc + j];
      float sn = sinT[s * 64 + dc + j];
      float o = sm[d0 + j] * c + sgn * sm[d0 + po + j] * sn;
      pk.b[j] = f2bf(o);
    }
    *reinterpret_cast<unsigned*>(Kd + ((size_t)g * S_LEN + s) * HEAD_DIM + dh) = pk.u;
  }

  // ---- V (512, transposed store Vt[g][d][s]) ----
  {
    float2 vv = *reinterpret_cast<const float2*>(row + QDIM + KDIM + tid * 2);
    int dv = tid * 2;
    int g = dv >> 7, d = dv & 127;
    Vt[(size_t)(g * HEAD_DIM + d) * S_LEN + s] = f2bf(vv.x);
    Vt[(size_t)(g * HEAD_DIM + d + 1) * S_LEN + s] = f2bf(vv.y);
  }
}

// ---------------- Causal GQA flash attention, swapped-operand form ----------------
// Q[NH][S][HD], K[NKV][S][HD], Vt[NKV][HD][S] bf16 -> AO[S][NH*HD] bf16.
// 4 independent waves/block (no barriers). Wave unit u = blockIdx.x*4+wave handles
// q rows [16u,16u+16) and the mirror [16*(255-u), +16) -> uniform 65 KV-tile units.
// Swapped QK^T: S^T[kv][q] = mfma(Kfrag, Qfrag) -> lane owns one q-row (col=l15);
// row softmax = in-lane over 16 regs + shfl_xor(16,32). Swapped PV: O^T[d][q] =
// mfma(Vfrag, Pfrag). P bounced via per-wave XOR-swizzled LDS (b64 writes, b128 reads).
__global__ __launch_bounds__(256) void k_attn(
    const unsigned short* __restrict__ Q, const unsigned short* __restrict__ K,
    const unsigned short* __restrict__ Vt, unsigned short* __restrict__ AO) {
  const int h = blockIdx.y;
  const int kvh = h >> 2;
  const int wave = threadIdx.x >> 6, lane = threadIdx.x & 63;
  const int l15 = lane & 15;
  const int gq = lane >> 4;
  const int koff = gq * 8;
  const unsigned short* Kg = K + (size_t)kvh * S_LEN * HEAD_DIM;
  const unsigned short* Vg = Vt + (size_t)kvh * HEAD_DIM * S_LEN;

  __shared__ unsigned short Plds[4][16 * 64];
  unsigned short* Pw = Plds[wave];
  const int swz = (l15 & 7) << 4;  // byte swizzle within the 128B P row

  const int u0 = blockIdx.x * 4 + wave;

#pragma unroll 1
  for (int ph = 0; ph < 2; ++ph) {
    const int u = ph ? (255 - u0) : u0;
    const int q0 = u * 16;
    const int NT = (u >> 2) + 1;   // KV tiles of 64 covering [0, q0+16)
    const int q_abs = q0 + l15;

    const unsigned short* Qp = Q + ((size_t)h * S_LEN + q0 + l15) * HEAD_DIM + koff;
    bf16x8 qf[4];
#pragma unroll
    for (int dt = 0; dt < 4; ++dt) qf[dt] = *reinterpret_cast<const bf16x8*>(Qp + dt * 32);

    f32x4 o[8] = {};
    float m = -1e30f, l = 0.f;

#pragma unroll 1
    for (int t = 0; t < NT; ++t) {
      const int kv0 = t * 64;
      // ---- QK^T (swapped): sc[kb] rows = kv, cols = q ----
      f32x4 sc[4];
#pragma unroll
      for (int kb = 0; kb < 4; ++kb) {
        f32x4 z = {0.f, 0.f, 0.f, 0.f};
        sc[kb] = z;
        const unsigned short* Kp = Kg + (size_t)(kv0 + kb * 16 + l15) * HEAD_DIM + koff;
#pragma unroll
        for (int dt = 0; dt < 4; ++dt) {
          bf16x8 kf = *reinterpret_cast<const bf16x8*>(Kp + dt * 32);
          sc[kb] = __builtin_amdgcn_mfma_f32_16x16x32_bf16(kf, qf[dt], sc[kb], 0, 0, 0);
        }
      }
      if (t == NT - 1) {  // diagonal tile: causal mask (kv = kv0+16kb+4gq+i, q = q_abs)
#pragma unroll
        for (int kb = 0; kb < 4; ++kb)
#pragma unroll
          for (int i = 0; i < 4; ++i)
            if (kv0 + kb * 16 + gq * 4 + i > q_abs) sc[kb][i] = -1e30f;
      }
      // ---- online softmax: lane-local row, 2 shfls for cross-group ----
      float pm = sc[0][0];
#pragma unroll
      for (int kb = 0; kb < 4; ++kb)
#pragma unroll
        for (int i = 0; i < 4; ++i) pm = fmaxf(pm, sc[kb][i]);
      pm = fmaxf(pm, __shfl_xor(pm, 16));
      pm = fmaxf(pm, __shfl_xor(pm, 32));
      if (!__all(pm <= m + 8.f)) {  // defer-max (T13): rescale only on real growth
        float mn = fmaxf(m, pm);
        float fac = exp2f((m - mn) * 1.44269504f);
#pragma unroll
        for (int df = 0; df < 8; ++df) o[df] *= fac;
        l *= fac;
        m = mn;
      }
      float rs = 0.f;
#pragma unroll
      for (int kb = 0; kb < 4; ++kb) {
        float p0 = exp2f((sc[kb][0] - m) * 1.44269504f);
        float p1 = exp2f((sc[kb][1] - m) * 1.44269504f);
        float p2 = exp2f((sc[kb][2] - m) * 1.44269504f);
        float p3 = exp2f((sc[kb][3] - m) * 1.44269504f);
        rs += (p0 + p1) + (p2 + p3);
        uint2 w;
        w.x = (unsigned)f2bf(p0) | ((unsigned)f2bf(p1) << 16);
        w.y = (unsigned)f2bf(p2) | ((unsigned)f2bf(p3) << 16);
        // P[q=l15][kv-local 4gq+16kb..+3], row 128B, byte col ^ swz (8B aligned)
        *reinterpret_cast<uint2*>(Pw + ((l15 * 128 + ((gq * 8 + kb * 32) ^ swz)) >> 1)) = w;
      }
      rs += __shfl_xor(rs, 16);
      rs += __shfl_xor(rs, 32);
      l += rs;
      asm volatile("s_waitcnt lgkmcnt(0)" ::: "memory");
      // ---- PV (swapped): o[df] rows = d, cols = q ----
#pragma unroll
      for (int c = 0; c < 2; ++c) {
        bf16x8 pa = *reinterpret_cast<const bf16x8*>(
            Pw + ((l15 * 128 + ((c * 64 + gq * 16) ^ swz)) >> 1));
#pragma unroll
        for (int df = 0; df < 8; ++df) {
          bf16x8 vf = *reinterpret_cast<const bf16x8*>(
              Vg + (size_t)(df * 16 + l15) * S_LEN + kv0 + c * 32 + koff);
          o[df] = __builtin_amdgcn_mfma_f32_16x16x32_bf16(vf, pa, o[df], 0, 0, 0);
        }
      }
    }
    // ---- epilogue: O^T[d][q] -> AO[q][h*128+d], 8B stores ----
    float inv = 1.0f / l;
#pragma unroll
    for (int df = 0; df < 8; ++df) {
      uint2 w;
      w.x = (unsigned)f2bf(o[df][0] * inv) | ((unsigned)f2bf(o[df][1] * inv) << 16);
      w.y = (unsigned)f2bf(o[df][2] * inv) | ((unsigned)f2bf(o[df][3] * inv) << 16);
      *reinterpret_cast<uint2*>(AO + (size_t)q_abs * QDIM + h * HEAD_DIM + df * 16 + gq * 4) = w;
    }
  }
}

extern "C" void kernel_launch(void* const* d_in, const int* in_sizes, int n_in,
                              void* d_out, int out_size, void* d_ws, size_t ws_size,
                              hipStream_t stream) {
  const float* hs = (const float*)d_in[0];
  const float* wq = (const float*)d_in[1];
  const float* wk = (const float*)d_in[2];
  const float* wv = (const float*)d_in[3];
  const float* wo = (const float*)d_in[4];
  const float* qnw = (const float*)d_in[5];
  const float* knw = (const float*)d_in[6];
  float* out = (float*)d_out;

  char* base = (char*)d_ws;
  unsigned short* Xb = (unsigned short*)base;                  // 16.78 MB (dead after GEMM1)
  unsigned short* Qb = Xb;                                     // reuse
  unsigned short* Wqkv = (unsigned short*)(base + 16777216);   // 12.58 MB (dead after GEMM1)
  unsigned short* Kb = Wqkv;                                   // reuse (4.19 MB)
  unsigned short* Vtb = (unsigned short*)(base + 16777216 + 4194304);  // reuse (4.19 MB)
  unsigned short* Wob = (unsigned short*)(base + 29360128);    // 8.39 MB (live to end)
  float* QKV = (float*)(base + 37748736);                      // 50.33 MB (dead after norm_rope)
  unsigned short* AOb = (unsigned short*)QKV;                  // reuse (16.78 MB)
  float* cosT = (float*)(base + 88080384);                     // 1 MB
  float* sinT = (float*)(base + 89128960);                     // 1 MB

  int n;
  n = S_LEN * HIDDEN / 4; k_cvt<<<(n + 255) / 256, 256, 0, stream>>>(hs, Xb, n);
  n = QDIM * HIDDEN / 4;  k_cvt<<<(n + 255) / 256, 256, 0, stream>>>(wq, Wqkv, n);
  n = KDIM * HIDDEN / 4;  k_cvt<<<(n + 255) / 256, 256, 0, stream>>>(wk, Wqkv + (size_t)QDIM * HIDDEN, n);
  n = KDIM * HIDDEN / 4;  k_cvt<<<(n + 255) / 256, 256, 0, stream>>>(wv, Wqkv + (size_t)(QDIM + KDIM) * HIDDEN, n);
  n = HIDDEN * QDIM / 4;  k_cvt<<<(n + 255) / 256, 256, 0, stream>>>(wo, Wob, n);
  k_rope_tab<<<(S_LEN * 64) / 256, 256, 0, stream>>>(cosT, sinT);

  k_gemm_bt<<<dim3(QKVD / BN, S_LEN / BM), 256, 0, stream>>>(Xb, Wqkv, QKV, S_LEN, QKVD, HIDDEN);
  k_norm_rope<<<S_LEN, 256, 0, stream>>>(QKV, qnw, knw, cosT, sinT, Qb, Kb, Vtb);
  k_attn<<<dim3(32, N_HEADS), 256, 0, stream>>>(Qb, Kb, Vtb, AOb);
  k_gemm_bt<<<dim3(QDIM / BN, S_LEN / BM), 256, 0, stream>>>(AOb, Wob, out, S_LEN, QDIM, HIDDEN);
}

// Round 3
// 627.824 us; speedup vs baseline: 1.4865x; 1.1898x over previous
//
#include <hip/hip_runtime.h>
#include <math.h>

#define S_LEN 4096
#define HIDDEN 2048
#define N_HEADS 16
#define N_KV 4
#define HEAD_DIM 128
#define QDIM 2048
#define KDIM 512
#define QKVD 3072
#define ATTN_SCALE 0.08838834764831845f

typedef __bf16 bf16x8 __attribute__((ext_vector_type(8)));
typedef float f32x4 __attribute__((ext_vector_type(4)));

__device__ __forceinline__ unsigned short f2bf(float x) {
  union { float f; unsigned u; } v; v.f = x;
  unsigned r = v.u + 0x7fffu + ((v.u >> 16) & 1u);
  return (unsigned short)(r >> 16);
}

__device__ __forceinline__ float wave_sum(float x) {
#pragma unroll
  for (int w = 32; w >= 1; w >>= 1) x += __shfl_xor(x, w);
  return x;
}

// ---------------- f32 -> bf16 convert (n4 = n/4) ----------------
__global__ void k_cvt(const float* __restrict__ s, unsigned short* __restrict__ d, int n4) {
  int i = blockIdx.x * blockDim.x + threadIdx.x;
  if (i >= n4) return;
  float4 v = reinterpret_cast<const float4*>(s)[i];
  ushort4 o;
  o.x = f2bf(v.x); o.y = f2bf(v.y); o.z = f2bf(v.z); o.w = f2bf(v.w);
  reinterpret_cast<ushort4*>(d)[i] = o;
}

// ---------------- RoPE cos/sin table [S][64] ----------------
__global__ void k_rope_tab(float* __restrict__ cosT, float* __restrict__ sinT) {
  int idx = blockIdx.x * blockDim.x + threadIdx.x;  // S*64
  int s = idx >> 6, d = idx & 63;
  float inv = powf(10000.0f, -(float)(2 * d) * (1.0f / 128.0f));
  float f = (float)s * inv;
  cosT[idx] = cosf(f);
  sinT[idx] = sinf(f);
}

// ---------------- GEMM: C[M,N] = A[M,K] * B[N,K]^T  (bf16 in, f32 out) ----------------
#define BM 128
#define BN 128
#define BK 32

__global__ __launch_bounds__(256) void k_gemm_bt(
    const unsigned short* __restrict__ A, const unsigned short* __restrict__ B,
    float* __restrict__ C, int M, int N, int K) {
  __shared__ unsigned short lds[2][BM * BK + BN * BK];
  const int tid = threadIdx.x;
  const int wave = tid >> 6, lane = tid & 63;
  const int brow = blockIdx.y * BM, bcol = blockIdx.x * BN;
  const int wr = wave >> 1, wc = wave & 1;
  const unsigned short* Ab = A + (size_t)brow * K;
  const unsigned short* Bb = B + (size_t)bcol * K;
  const int r0 = tid >> 2;       // 0..63
  const int c0 = (tid & 3) * 8;  // element col offset within BK

  f32x4 acc[4][4] = {};

#pragma unroll
  for (int c = 0; c < 2; ++c) {
    __builtin_amdgcn_global_load_lds(
        (const __attribute__((address_space(1))) void*)(Ab + (size_t)(c * 64 + r0) * K + c0),
        (__attribute__((address_space(3))) void*)(&lds[0][(c * 64 + r0) * BK + c0]), 16, 0, 0);
    __builtin_amdgcn_global_load_lds(
        (const __attribute__((address_space(1))) void*)(Bb + (size_t)(c * 64 + r0) * K + c0),
        (__attribute__((address_space(3))) void*)(&lds[0][BM * BK + (c * 64 + r0) * BK + c0]), 16, 0, 0);
  }

  const int KT = K / BK;
  const int arow = wr * 64 + (lane & 15);
  const int brow2 = wc * 64 + (lane & 15);
  const int koff = (lane >> 4) * 8;

  for (int kt = 0; kt < KT; ++kt) {
    if (kt + 1 < KT) {
      const int k0 = (kt + 1) * BK;
      const int buf = (kt + 1) & 1;
#pragma unroll
      for (int c = 0; c < 2; ++c) {
        __builtin_amdgcn_global_load_lds(
            (const __attribute__((address_space(1))) void*)(Ab + (size_t)(c * 64 + r0) * K + k0 + c0),
            (__attribute__((address_space(3))) void*)(&lds[buf][(c * 64 + r0) * BK + c0]), 16, 0, 0);
        __builtin_amdgcn_global_load_lds(
            (const __attribute__((address_space(1))) void*)(Bb + (size_t)(c * 64 + r0) * K + k0 + c0),
            (__attribute__((address_space(3))) void*)(&lds[buf][BM * BK + (c * 64 + r0) * BK + c0]), 16, 0, 0);
      }
    }
    __syncthreads();
    const unsigned short* la = &lds[kt & 1][0];
    const unsigned short* lb = &lds[kt & 1][BM * BK];
    bf16x8 a[4], b[4];
#pragma unroll
    for (int m = 0; m < 4; ++m)
      a[m] = *reinterpret_cast<const bf16x8*>(la + (arow + m * 16) * BK + koff);
#pragma unroll
    for (int n = 0; n < 4; ++n)
      b[n] = *reinterpret_cast<const bf16x8*>(lb + (brow2 + n * 16) * BK + koff);
#pragma unroll
    for (int m = 0; m < 4; ++m)
#pragma unroll
      for (int n = 0; n < 4; ++n)
        acc[m][n] = __builtin_amdgcn_mfma_f32_16x16x32_bf16(a[m], b[n], acc[m][n], 0, 0, 0);
    __syncthreads();
  }

  const int crow = brow + wr * 64 + (lane >> 4) * 4;
  const int ccol = bcol + wc * 64 + (lane & 15);
#pragma unroll
  for (int m = 0; m < 4; ++m)
#pragma unroll
    for (int n = 0; n < 4; ++n)
#pragma unroll
      for (int i = 0; i < 4; ++i)
        C[(size_t)(crow + m * 16 + i) * N + ccol + n * 16] = acc[m][n][i];
}

// ---------------- RMSNorm + RoPE + layout ----------------
__global__ __launch_bounds__(256) void k_norm_rope(
    const float* __restrict__ QKV, const float* __restrict__ qw, const float* __restrict__ kw,
    const float* __restrict__ cosT, const float* __restrict__ sinT,
    unsigned short* __restrict__ Q, unsigned short* __restrict__ Kd, unsigned short* __restrict__ Vt) {
  const int s = blockIdx.x;
  const int tid = threadIdx.x;
  const int lane = tid & 63, wave = tid >> 6;
  const float* row = QKV + (size_t)s * QKVD;
  __shared__ float sm[QDIM];
  __shared__ float red[4];

  // ---- Q (2048, 8 per thread) ----
  float qv[8];
  *reinterpret_cast<float4*>(&qv[0]) = reinterpret_cast<const float4*>(row)[tid * 2];
  *reinterpret_cast<float4*>(&qv[4]) = reinterpret_cast<const float4*>(row)[tid * 2 + 1];
  float ss = 0;
#pragma unroll
  for (int j = 0; j < 8; ++j) ss += qv[j] * qv[j];
  ss = wave_sum(ss);
  if (lane == 0) red[wave] = ss;
  __syncthreads();
  float tot = red[0] + red[1] + red[2] + red[3];
  float qs = rsqrtf(tot * (1.0f / QDIM) + 1e-5f) * ATTN_SCALE;
#pragma unroll
  for (int j = 0; j < 8; ++j) sm[tid * 8 + j] = qv[j] * qs * qw[tid * 8 + j];
  __syncthreads();
  {
    const int d0 = tid * 8;
    const int h = d0 >> 7;
    const int dh = d0 & 127;
    const int dc = dh & 63;
    const bool lo = dh < 64;
    const float sgn = lo ? -1.0f : 1.0f;
    const int po = lo ? 64 : -64;
    union { unsigned short b[8]; uint4 u; } pk;
#pragma unroll
    for (int j = 0; j < 8; ++j) {
      float c = cosT[s * 64 + dc + j];
      float sn = sinT[s * 64 + dc + j];
      float o = sm[d0 + j] * c + sgn * sm[d0 + po + j] * sn;
      pk.b[j] = f2bf(o);
    }
    *reinterpret_cast<uint4*>(Q + ((size_t)h * S_LEN + s) * HEAD_DIM + dh) = pk.u;
  }
  __syncthreads();

  // ---- K (512, 2 per thread) ----
  float2 kvp = *reinterpret_cast<const float2*>(row + QDIM + tid * 2);
  ss = kvp.x * kvp.x + kvp.y * kvp.y;
  ss = wave_sum(ss);
  if (lane == 0) red[wave] = ss;
  __syncthreads();
  tot = red[0] + red[1] + red[2] + red[3];
  float ks = rsqrtf(tot * (1.0f / KDIM) + 1e-5f);
  sm[tid * 2] = kvp.x * ks * kw[tid * 2];
  sm[tid * 2 + 1] = kvp.y * ks * kw[tid * 2 + 1];
  __syncthreads();
  {
    const int d0 = tid * 2;
    const int g = d0 >> 7;
    const int dh = d0 & 127;
    const int dc = dh & 63;
    const bool lo = dh < 64;
    const float sgn = lo ? -1.0f : 1.0f;
    const int po = lo ? 64 : -64;
    union { unsigned short b[2]; unsigned u; } pk;
#pragma unroll
    for (int j = 0; j < 2; ++j) {
      float c = cosT[s * 64 + dc + j];
      float sn = sinT[s * 64 + dc + j];
      float o = sm[d0 + j] * c + sgn * sm[d0 + po + j] * sn;
      pk.b[j] = f2bf(o);
    }
    *reinterpret_cast<unsigned*>(Kd + ((size_t)g * S_LEN + s) * HEAD_DIM + dh) = pk.u;
  }

  // ---- V (512, transposed store Vt[g][d][s]) ----
  {
    float2 vv = *reinterpret_cast<const float2*>(row + QDIM + KDIM + tid * 2);
    int dv = tid * 2;
    int g = dv >> 7, d = dv & 127;
    Vt[(size_t)(g * HEAD_DIM + d) * S_LEN + s] = f2bf(vv.x);
    Vt[(size_t)(g * HEAD_DIM + d + 1) * S_LEN + s] = f2bf(vv.y);
  }
}

// ---------------- Causal GQA flash attention, swapped-operand, ILP-staged ----------------
// ONE wave per block (__launch_bounds__(64,2) -> 256 VGPR budget). Per KV-tile of 64:
// all 16 K-fragment loads AND all 16 V-fragment loads are issued into registers up
// front (32 loads in flight), then QK^T MFMAs, lane-local online softmax, P via
// XOR-swizzled LDS bounce, PV MFMAs. Triangle pairing (u, 255-u) keeps work uniform.
__global__ __launch_bounds__(64, 2) void k_attn(
    const unsigned short* __restrict__ Q, const unsigned short* __restrict__ K,
    const unsigned short* __restrict__ Vt, unsigned short* __restrict__ AO) {
  const int h = blockIdx.y;
  const int kvh = h >> 2;
  const int lane = threadIdx.x & 63;
  const int l15 = lane & 15;
  const int gq = lane >> 4;
  const int koff = gq * 8;
  const unsigned short* Kg = K + (size_t)kvh * S_LEN * HEAD_DIM;
  const unsigned short* Vg = Vt + (size_t)kvh * HEAD_DIM * S_LEN;

  __shared__ unsigned short Pw[16 * 64];
  const int swz = (l15 & 7) << 4;  // byte swizzle within the 128B P row

  const int u0 = blockIdx.x;

#pragma unroll 1
  for (int ph = 0; ph < 2; ++ph) {
    const int u = ph ? (255 - u0) : u0;
    const int q0 = u * 16;
    const int NT = (u >> 2) + 1;   // KV tiles of 64 covering [0, q0+16)
    const int q_abs = q0 + l15;

    const unsigned short* Qp = Q + ((size_t)h * S_LEN + q0 + l15) * HEAD_DIM + koff;
    bf16x8 qf[4];
#pragma unroll
    for (int dt = 0; dt < 4; ++dt) qf[dt] = *reinterpret_cast<const bf16x8*>(Qp + dt * 32);

    f32x4 o[8] = {};
    float m = -1e30f, l = 0.f;

#pragma unroll 1
    for (int t = 0; t < NT; ++t) {
      const int kv0 = t * 64;
      // ---- issue ALL K and V fragment loads up front (32 in flight) ----
      bf16x8 kf[16];
#pragma unroll
      for (int kb = 0; kb < 4; ++kb) {
        const unsigned short* Kp = Kg + (size_t)(kv0 + kb * 16 + l15) * HEAD_DIM + koff;
#pragma unroll
        for (int dt = 0; dt < 4; ++dt)
          kf[kb * 4 + dt] = *reinterpret_cast<const bf16x8*>(Kp + dt * 32);
      }
      bf16x8 vf[16];
#pragma unroll
      for (int df = 0; df < 8; ++df) {
        const unsigned short* Vp = Vg + (size_t)(df * 16 + l15) * S_LEN + kv0 + koff;
#pragma unroll
        for (int c = 0; c < 2; ++c)
          vf[df * 2 + c] = *reinterpret_cast<const bf16x8*>(Vp + c * 32);
      }
      // ---- QK^T (swapped): sc[kb] rows = kv, cols = q ----
      f32x4 sc[4];
#pragma unroll
      for (int kb = 0; kb < 4; ++kb) {
        f32x4 z = {0.f, 0.f, 0.f, 0.f};
        sc[kb] = z;
#pragma unroll
        for (int dt = 0; dt < 4; ++dt)
          sc[kb] = __builtin_amdgcn_mfma_f32_16x16x32_bf16(kf[kb * 4 + dt], qf[dt], sc[kb], 0, 0, 0);
      }
      if (t == NT - 1) {  // diagonal tile: causal mask (kv = kv0+16kb+4gq+i, q = q_abs)
#pragma unroll
        for (int kb = 0; kb < 4; ++kb)
#pragma unroll
          for (int i = 0; i < 4; ++i)
            if (kv0 + kb * 16 + gq * 4 + i > q_abs) sc[kb][i] = -1e30f;
      }
      // ---- online softmax: lane-local row, 2 shfls for cross-group ----
      float pm = sc[0][0];
#pragma unroll
      for (int kb = 0; kb < 4; ++kb)
#pragma unroll
        for (int i = 0; i < 4; ++i) pm = fmaxf(pm, sc[kb][i]);
      pm = fmaxf(pm, __shfl_xor(pm, 16));
      pm = fmaxf(pm, __shfl_xor(pm, 32));
      if (!__all(pm <= m + 8.f)) {  // defer-max (T13): rescale only on real growth
        float mn = fmaxf(m, pm);
        float fac = exp2f((m - mn) * 1.44269504f);
#pragma unroll
        for (int df = 0; df < 8; ++df) o[df] *= fac;
        l *= fac;
        m = mn;
      }
      float rs = 0.f;
#pragma unroll
      for (int kb = 0; kb < 4; ++kb) {
        float p0 = exp2f((sc[kb][0] - m) * 1.44269504f);
        float p1 = exp2f((sc[kb][1] - m) * 1.44269504f);
        float p2 = exp2f((sc[kb][2] - m) * 1.44269504f);
        float p3 = exp2f((sc[kb][3] - m) * 1.44269504f);
        rs += (p0 + p1) + (p2 + p3);
        uint2 w;
        w.x = (unsigned)f2bf(p0) | ((unsigned)f2bf(p1) << 16);
        w.y = (unsigned)f2bf(p2) | ((unsigned)f2bf(p3) << 16);
        // P[q=l15][kv-local 4gq+16kb..+3], row 128B, byte col ^ swz (8B aligned)
        *reinterpret_cast<uint2*>(Pw + ((l15 * 128 + ((gq * 8 + kb * 32) ^ swz)) >> 1)) = w;
      }
      rs += __shfl_xor(rs, 16);
      rs += __shfl_xor(rs, 32);
      l += rs;
      asm volatile("s_waitcnt lgkmcnt(0)" ::: "memory");
      // ---- PV (swapped): o[df] rows = d, cols = q ----
#pragma unroll
      for (int c = 0; c < 2; ++c) {
        bf16x8 pa = *reinterpret_cast<const bf16x8*>(
            Pw + ((l15 * 128 + ((c * 64 + gq * 16) ^ swz)) >> 1));
#pragma unroll
        for (int df = 0; df < 8; ++df)
          o[df] = __builtin_amdgcn_mfma_f32_16x16x32_bf16(vf[df * 2 + c], pa, o[df], 0, 0, 0);
      }
    }
    // ---- epilogue: O^T[d][q] -> AO[q][h*128+d], 8B stores ----
    float inv = 1.0f / l;
#pragma unroll
    for (int df = 0; df < 8; ++df) {
      uint2 w;
      w.x = (unsigned)f2bf(o[df][0] * inv) | ((unsigned)f2bf(o[df][1] * inv) << 16);
      w.y = (unsigned)f2bf(o[df][2] * inv) | ((unsigned)f2bf(o[df][3] * inv) << 16);
      *reinterpret_cast<uint2*>(AO + (size_t)q_abs * QDIM + h * HEAD_DIM + df * 16 + gq * 4) = w;
    }
  }
}

extern "C" void kernel_launch(void* const* d_in, const int* in_sizes, int n_in,
                              void* d_out, int out_size, void* d_ws, size_t ws_size,
                              hipStream_t stream) {
  const float* hs = (const float*)d_in[0];
  const float* wq = (const float*)d_in[1];
  const float* wk = (const float*)d_in[2];
  const float* wv = (const float*)d_in[3];
  const float* wo = (const float*)d_in[4];
  const float* qnw = (const float*)d_in[5];
  const float* knw = (const float*)d_in[6];
  float* out = (float*)d_out;

  char* base = (char*)d_ws;
  unsigned short* Xb = (unsigned short*)base;                  // 16.78 MB (dead after GEMM1)
  unsigned short* Qb = Xb;                                     // reuse
  unsigned short* Wqkv = (unsigned short*)(base + 16777216);   // 12.58 MB (dead after GEMM1)
  unsigned short* Kb = Wqkv;                                   // reuse (4.19 MB)
  unsigned short* Vtb = (unsigned short*)(base + 16777216 + 4194304);  // reuse (4.19 MB)
  unsigned short* Wob = (unsigned short*)(base + 29360128);    // 8.39 MB (live to end)
  float* QKV = (float*)(base + 37748736);                      // 50.33 MB (dead after norm_rope)
  unsigned short* AOb = (unsigned short*)QKV;                  // reuse (16.78 MB)
  float* cosT = (float*)(base + 88080384);                     // 1 MB
  float* sinT = (float*)(base + 89128960);                     // 1 MB

  int n;
  n = S_LEN * HIDDEN / 4; k_cvt<<<(n + 255) / 256, 256, 0, stream>>>(hs, Xb, n);
  n = QDIM * HIDDEN / 4;  k_cvt<<<(n + 255) / 256, 256, 0, stream>>>(wq, Wqkv, n);
  n = KDIM * HIDDEN / 4;  k_cvt<<<(n + 255) / 256, 256, 0, stream>>>(wk, Wqkv + (size_t)QDIM * HIDDEN, n);
  n = KDIM * HIDDEN / 4;  k_cvt<<<(n + 255) / 256, 256, 0, stream>>>(wv, Wqkv + (size_t)(QDIM + KDIM) * HIDDEN, n);
  n = HIDDEN * QDIM / 4;  k_cvt<<<(n + 255) / 256, 256, 0, stream>>>(wo, Wob, n);
  k_rope_tab<<<(S_LEN * 64) / 256, 256, 0, stream>>>(cosT, sinT);

  k_gemm_bt<<<dim3(QKVD / BN, S_LEN / BM), 256, 0, stream>>>(Xb, Wqkv, QKV, S_LEN, QKVD, HIDDEN);
  k_norm_rope<<<S_LEN, 256, 0, stream>>>(QKV, qnw, knw, cosT, sinT, Qb, Kb, Vtb);
  k_attn<<<dim3(128, N_HEADS), 64, 0, stream>>>(Qb, Kb, Vtb, AOb);
  k_gemm_bt<<<dim3(QDIM / BN, S_LEN / BM), 256, 0, stream>>>(AOb, Wob, out, S_LEN, QDIM, HIDDEN);
}

// Round 4
// 449.514 us; speedup vs baseline: 2.0761x; 1.3967x over previous
//
#include <hip/hip_runtime.h>
#include <math.h>

#define S_LEN 4096
#define HIDDEN 2048
#define N_HEADS 16
#define N_KV 4
#define HEAD_DIM 128
#define QDIM 2048
#define KDIM 512
#define QKVD 3072
#define ATTN_SCALE 0.08838834764831845f

typedef __bf16 bf16x8 __attribute__((ext_vector_type(8)));
typedef float f32x4 __attribute__((ext_vector_type(4)));

__device__ __forceinline__ unsigned short f2bf(float x) {
  union { float f; unsigned u; } v; v.f = x;
  unsigned r = v.u + 0x7fffu + ((v.u >> 16) & 1u);
  return (unsigned short)(r >> 16);
}

__device__ __forceinline__ float wave_sum(float x) {
#pragma unroll
  for (int w = 32; w >= 1; w >>= 1) x += __shfl_xor(x, w);
  return x;
}

// ---------------- f32 -> bf16 convert (n4 = n/4) ----------------
__global__ void k_cvt(const float* __restrict__ s, unsigned short* __restrict__ d, int n4) {
  int i = blockIdx.x * blockDim.x + threadIdx.x;
  if (i >= n4) return;
  float4 v = reinterpret_cast<const float4*>(s)[i];
  ushort4 o;
  o.x = f2bf(v.x); o.y = f2bf(v.y); o.z = f2bf(v.z); o.w = f2bf(v.w);
  reinterpret_cast<ushort4*>(d)[i] = o;
}

// ---------------- RoPE cos/sin table [S][64] ----------------
__global__ void k_rope_tab(float* __restrict__ cosT, float* __restrict__ sinT) {
  int idx = blockIdx.x * blockDim.x + threadIdx.x;  // S*64
  int s = idx >> 6, d = idx & 63;
  float inv = powf(10000.0f, -(float)(2 * d) * (1.0f / 128.0f));
  float f = (float)s * inv;
  cosT[idx] = cosf(f);
  sinT[idx] = sinf(f);
}

// ---------------- GEMM: C[M,N] = A[M,K] * B[N,K]^T  (bf16 in, f32 out) ----------------
#define BM 128
#define BN 128
#define BK 32

__global__ __launch_bounds__(256) void k_gemm_bt(
    const unsigned short* __restrict__ A, const unsigned short* __restrict__ B,
    float* __restrict__ C, int M, int N, int K) {
  __shared__ unsigned short lds[2][BM * BK + BN * BK];
  const int tid = threadIdx.x;
  const int wave = tid >> 6, lane = tid & 63;
  const int brow = blockIdx.y * BM, bcol = blockIdx.x * BN;
  const int wr = wave >> 1, wc = wave & 1;
  const unsigned short* Ab = A + (size_t)brow * K;
  const unsigned short* Bb = B + (size_t)bcol * K;
  const int r0 = tid >> 2;       // 0..63
  const int c0 = (tid & 3) * 8;  // element col offset within BK

  f32x4 acc[4][4] = {};

#pragma unroll
  for (int c = 0; c < 2; ++c) {
    __builtin_amdgcn_global_load_lds(
        (const __attribute__((address_space(1))) void*)(Ab + (size_t)(c * 64 + r0) * K + c0),
        (__attribute__((address_space(3))) void*)(&lds[0][(c * 64 + r0) * BK + c0]), 16, 0, 0);
    __builtin_amdgcn_global_load_lds(
        (const __attribute__((address_space(1))) void*)(Bb + (size_t)(c * 64 + r0) * K + c0),
        (__attribute__((address_space(3))) void*)(&lds[0][BM * BK + (c * 64 + r0) * BK + c0]), 16, 0, 0);
  }

  const int KT = K / BK;
  const int arow = wr * 64 + (lane & 15);
  const int brow2 = wc * 64 + (lane & 15);
  const int koff = (lane >> 4) * 8;

  for (int kt = 0; kt < KT; ++kt) {
    if (kt + 1 < KT) {
      const int k0 = (kt + 1) * BK;
      const int buf = (kt + 1) & 1;
#pragma unroll
      for (int c = 0; c < 2; ++c) {
        __builtin_amdgcn_global_load_lds(
            (const __attribute__((address_space(1))) void*)(Ab + (size_t)(c * 64 + r0) * K + k0 + c0),
            (__attribute__((address_space(3))) void*)(&lds[buf][(c * 64 + r0) * BK + c0]), 16, 0, 0);
        __builtin_amdgcn_global_load_lds(
            (const __attribute__((address_space(1))) void*)(Bb + (size_t)(c * 64 + r0) * K + k0 + c0),
            (__attribute__((address_space(3))) void*)(&lds[buf][BM * BK + (c * 64 + r0) * BK + c0]), 16, 0, 0);
      }
    }
    __syncthreads();
    const unsigned short* la = &lds[kt & 1][0];
    const unsigned short* lb = &lds[kt & 1][BM * BK];
    bf16x8 a[4], b[4];
#pragma unroll
    for (int m = 0; m < 4; ++m)
      a[m] = *reinterpret_cast<const bf16x8*>(la + (arow + m * 16) * BK + koff);
#pragma unroll
    for (int n = 0; n < 4; ++n)
      b[n] = *reinterpret_cast<const bf16x8*>(lb + (brow2 + n * 16) * BK + koff);
#pragma unroll
    for (int m = 0; m < 4; ++m)
#pragma unroll
      for (int n = 0; n < 4; ++n)
        acc[m][n] = __builtin_amdgcn_mfma_f32_16x16x32_bf16(a[m], b[n], acc[m][n], 0, 0, 0);
    __syncthreads();
  }

  const int crow = brow + wr * 64 + (lane >> 4) * 4;
  const int ccol = bcol + wc * 64 + (lane & 15);
#pragma unroll
  for (int m = 0; m < 4; ++m)
#pragma unroll
    for (int n = 0; n < 4; ++n)
#pragma unroll
      for (int i = 0; i < 4; ++i)
        C[(size_t)(crow + m * 16 + i) * N + ccol + n * 16] = acc[m][n][i];
}

// ---------------- RMSNorm + RoPE + layout ----------------
__global__ __launch_bounds__(256) void k_norm_rope(
    const float* __restrict__ QKV, const float* __restrict__ qw, const float* __restrict__ kw,
    const float* __restrict__ cosT, const float* __restrict__ sinT,
    unsigned short* __restrict__ Q, unsigned short* __restrict__ Kd, unsigned short* __restrict__ Vt) {
  const int s = blockIdx.x;
  const int tid = threadIdx.x;
  const int lane = tid & 63, wave = tid >> 6;
  const float* row = QKV + (size_t)s * QKVD;
  __shared__ float sm[QDIM];
  __shared__ float red[4];

  // ---- Q (2048, 8 per thread) ----
  float qv[8];
  *reinterpret_cast<float4*>(&qv[0]) = reinterpret_cast<const float4*>(row)[tid * 2];
  *reinterpret_cast<float4*>(&qv[4]) = reinterpret_cast<const float4*>(row)[tid * 2 + 1];
  float ss = 0;
#pragma unroll
  for (int j = 0; j < 8; ++j) ss += qv[j] * qv[j];
  ss = wave_sum(ss);
  if (lane == 0) red[wave] = ss;
  __syncthreads();
  float tot = red[0] + red[1] + red[2] + red[3];
  float qs = rsqrtf(tot * (1.0f / QDIM) + 1e-5f) * ATTN_SCALE;
#pragma unroll
  for (int j = 0; j < 8; ++j) sm[tid * 8 + j] = qv[j] * qs * qw[tid * 8 + j];
  __syncthreads();
  {
    const int d0 = tid * 8;
    const int h = d0 >> 7;
    const int dh = d0 & 127;
    const int dc = dh & 63;
    const bool lo = dh < 64;
    const float sgn = lo ? -1.0f : 1.0f;
    const int po = lo ? 64 : -64;
    union { unsigned short b[8]; uint4 u; } pk;
#pragma unroll
    for (int j = 0; j < 8; ++j) {
      float c = cosT[s * 64 + dc + j];
      float sn = sinT[s * 64 + dc + j];
      float o = sm[d0 + j] * c + sgn * sm[d0 + po + j] * sn;
      pk.b[j] = f2bf(o);
    }
    *reinterpret_cast<uint4*>(Q + ((size_t)h * S_LEN + s) * HEAD_DIM + dh) = pk.u;
  }
  __syncthreads();

  // ---- K (512, 2 per thread) ----
  float2 kvp = *reinterpret_cast<const float2*>(row + QDIM + tid * 2);
  ss = kvp.x * kvp.x + kvp.y * kvp.y;
  ss = wave_sum(ss);
  if (lane == 0) red[wave] = ss;
  __syncthreads();
  tot = red[0] + red[1] + red[2] + red[3];
  float ks = rsqrtf(tot * (1.0f / KDIM) + 1e-5f);
  sm[tid * 2] = kvp.x * ks * kw[tid * 2];
  sm[tid * 2 + 1] = kvp.y * ks * kw[tid * 2 + 1];
  __syncthreads();
  {
    const int d0 = tid * 2;
    const int g = d0 >> 7;
    const int dh = d0 & 127;
    const int dc = dh & 63;
    const bool lo = dh < 64;
    const float sgn = lo ? -1.0f : 1.0f;
    const int po = lo ? 64 : -64;
    union { unsigned short b[2]; unsigned u; } pk;
#pragma unroll
    for (int j = 0; j < 2; ++j) {
      float c = cosT[s * 64 + dc + j];
      float sn = sinT[s * 64 + dc + j];
      float o = sm[d0 + j] * c + sgn * sm[d0 + po + j] * sn;
      pk.b[j] = f2bf(o);
    }
    *reinterpret_cast<unsigned*>(Kd + ((size_t)g * S_LEN + s) * HEAD_DIM + dh) = pk.u;
  }

  // ---- V (512, transposed store Vt[g][d][s]) ----
  {
    float2 vv = *reinterpret_cast<const float2*>(row + QDIM + KDIM + tid * 2);
    int dv = tid * 2;
    int g = dv >> 7, d = dv & 127;
    Vt[(size_t)(g * HEAD_DIM + d) * S_LEN + s] = f2bf(vv.x);
    Vt[(size_t)(g * HEAD_DIM + d + 1) * S_LEN + s] = f2bf(vv.y);
  }
}

// ---------------- Causal GQA flash attention: LDS-shared KV, GQA head-sharing ----------
// Block = 512 thr / 8 waves = 4 heads (one KV group) x 2 q-subblocks of 32 rows.
// K tile [64 kv][128 d] + V tile [128 d][64 kv] staged once per block into XOR-swizzled
// LDS (byte ^= (row&7)<<4); each wave reads fragments once, reuses across its 2 q-frags.
// Staging: reg-staged, loads for t+1 issued right after barrier2 so they fly under
// compute(t); plain __syncthreads preserves overlap with this placement.
__global__ __launch_bounds__(512, 2) void k_attn(
    const unsigned short* __restrict__ Q, const unsigned short* __restrict__ K,
    const unsigned short* __restrict__ Vt, unsigned short* __restrict__ AO) {
  const int g = blockIdx.y;
  const int qt = blockIdx.x;                 // 0..63, block q-rows [qt*64, qt*64+64)
  const int tid = threadIdx.x;
  const int w = tid >> 6, lane = tid & 63;
  const int l15 = lane & 15, gq = lane >> 4;
  const int myswz = (l15 & 7) << 4;
  const int h = g * 4 + (w & 3);
  const int q0w = qt * 64 + (w >> 2) * 32;   // this wave's 32-row base
  const int NT = qt + 1;                     // KV tiles of 64

  const unsigned short* Kg = K + (size_t)g * S_LEN * HEAD_DIM;
  const unsigned short* Vg = Vt + (size_t)g * HEAD_DIM * S_LEN;

  __shared__ unsigned short lds[32768];      // [0,16K)B K | [16K,32K)B V | [32K,64K)B P
  char* ldsb = (char*)lds;

  // ---- staging assignment: 512 threads x 64B; threads <256 stage K, >=256 stage V ----
  const bool isK = tid < 256;
  const int srow = isK ? (tid >> 2) : ((tid - 256) >> 1);
  const int scolb = isK ? ((tid & 3) * 64) : ((tid & 1) * 64);
  const char* sp = isK ? (const char*)Kg + (size_t)srow * 256 + scolb
                       : (const char*)Vg + (size_t)srow * (S_LEN * 2) + scolb;
  const int sstep = isK ? 64 * 256 : 64 * 2;  // bytes per KV-tile advance
  char* const dbase = (isK ? ldsb : ldsb + 16384) + srow * (isK ? 256 : 128);
  const int dswz = (srow & 7) << 4;

  float4 stg[4];
#pragma unroll
  for (int i = 0; i < 4; ++i) stg[i] = *reinterpret_cast<const float4*>(sp + i * 16);
  sp += sstep;

  // ---- Q fragments (2 frags of 16 rows) ----
  bf16x8 qf[2][4];
#pragma unroll
  for (int f = 0; f < 2; ++f)
#pragma unroll
    for (int dt = 0; dt < 4; ++dt)
      qf[f][dt] = *reinterpret_cast<const bf16x8*>(
          Q + ((size_t)h * S_LEN + q0w + f * 16 + l15) * HEAD_DIM + dt * 32 + gq * 8);

  f32x4 o[2][8] = {};
  float m[2] = {-1e30f, -1e30f}, l[2] = {0.f, 0.f};

  unsigned short* const Pp0 = lds + 16384 + (w * 2 + 0) * 1024;  // ushort idx; 2KB per frag
  unsigned short* const Pp1 = lds + 16384 + (w * 2 + 1) * 1024;

#pragma unroll 1
  for (int t = 0; t < NT; ++t) {
    __syncthreads();  // all waves done reading tile t-1 (also drains stg loads)
#pragma unroll
    for (int i = 0; i < 4; ++i)
      *reinterpret_cast<float4*>(dbase + ((scolb + i * 16) ^ dswz)) = stg[i];
    __syncthreads();  // tile t visible
    if (t + 1 < NT) {  // issue t+1 loads now: in flight under compute(t)
#pragma unroll
      for (int i = 0; i < 4; ++i) stg[i] = *reinterpret_cast<const float4*>(sp + i * 16);
      sp += sstep;
    }
    const int kv0 = t * 64;
    // ---- QK^T (swapped): sc rows = kv, cols = q ----
    f32x4 sc[2][4];
#pragma unroll
    for (int f = 0; f < 2; ++f)
#pragma unroll
      for (int kb = 0; kb < 4; ++kb) sc[f][kb] = (f32x4){0.f, 0.f, 0.f, 0.f};
#pragma unroll
    for (int kb = 0; kb < 4; ++kb) {
      const int krow = kb * 16 + l15;
      bf16x8 kf[4];
#pragma unroll
      for (int dt = 0; dt < 4; ++dt)
        kf[dt] = *reinterpret_cast<const bf16x8*>(
            ldsb + krow * 256 + ((dt * 64 + gq * 16) ^ myswz));
#pragma unroll
      for (int f = 0; f < 2; ++f)
#pragma unroll
        for (int dt = 0; dt < 4; ++dt)
          sc[f][kb] = __builtin_amdgcn_mfma_f32_16x16x32_bf16(kf[dt], qf[f][dt], sc[f][kb], 0, 0, 0);
    }
    if (t == NT - 1) {  // diagonal: mask kv > q
#pragma unroll
      for (int f = 0; f < 2; ++f)
#pragma unroll
        for (int kb = 0; kb < 4; ++kb)
#pragma unroll
          for (int i = 0; i < 4; ++i)
            if (kv0 + kb * 16 + gq * 4 + i > q0w + f * 16 + l15) sc[f][kb][i] = -1e30f;
    }
    // ---- online softmax per frag (lane-local + 2 shfl) ----
#pragma unroll
    for (int f = 0; f < 2; ++f) {
      float pm = sc[f][0][0];
#pragma unroll
      for (int kb = 0; kb < 4; ++kb)
#pragma unroll
        for (int i = 0; i < 4; ++i) pm = fmaxf(pm, sc[f][kb][i]);
      pm = fmaxf(pm, __shfl_xor(pm, 16));
      pm = fmaxf(pm, __shfl_xor(pm, 32));
      if (!__all(pm <= m[f] + 8.f)) {  // defer-max (T13)
        float mn = fmaxf(m[f], pm);
        float fac = exp2f((m[f] - mn) * 1.44269504f);
#pragma unroll
        for (int df = 0; df < 8; ++df) o[f][df] *= fac;
        l[f] *= fac;
        m[f] = mn;
      }
      unsigned short* Pf = f ? Pp1 : Pp0;
      float rs = 0.f;
#pragma unroll
      for (int kb = 0; kb < 4; ++kb) {
        float p0 = exp2f((sc[f][kb][0] - m[f]) * 1.44269504f);
        float p1 = exp2f((sc[f][kb][1] - m[f]) * 1.44269504f);
        float p2 = exp2f((sc[f][kb][2] - m[f]) * 1.44269504f);
        float p3 = exp2f((sc[f][kb][3] - m[f]) * 1.44269504f);
        rs += (p0 + p1) + (p2 + p3);
        uint2 pw;
        pw.x = (unsigned)f2bf(p0) | ((unsigned)f2bf(p1) << 16);
        pw.y = (unsigned)f2bf(p2) | ((unsigned)f2bf(p3) << 16);
        *reinterpret_cast<uint2*>(
            reinterpret_cast<char*>(Pf) + l15 * 128 + ((kb * 32 + gq * 8) ^ myswz)) = pw;
      }
      rs += __shfl_xor(rs, 16);
      rs += __shfl_xor(rs, 32);
      l[f] += rs;
    }
    asm volatile("s_waitcnt lgkmcnt(0)" ::: "memory");
    // ---- PV (swapped): o rows = d, cols = q; vf shared across both frags ----
#pragma unroll
    for (int c = 0; c < 2; ++c) {
      bf16x8 pa0 = *reinterpret_cast<const bf16x8*>(
          reinterpret_cast<char*>(Pp0) + l15 * 128 + ((c * 64 + gq * 16) ^ myswz));
      bf16x8 pa1 = *reinterpret_cast<const bf16x8*>(
          reinterpret_cast<char*>(Pp1) + l15 * 128 + ((c * 64 + gq * 16) ^ myswz));
#pragma unroll
      for (int df = 0; df < 8; ++df) {
        const int vrow = df * 16 + l15;
        bf16x8 vf = *reinterpret_cast<const bf16x8*>(
            ldsb + 16384 + vrow * 128 + ((c * 64 + gq * 16) ^ myswz));
        o[0][df] = __builtin_amdgcn_mfma_f32_16x16x32_bf16(vf, pa0, o[0][df], 0, 0, 0);
        o[1][df] = __builtin_amdgcn_mfma_f32_16x16x32_bf16(vf, pa1, o[1][df], 0, 0, 0);
      }
    }
  }
  // ---- epilogue: O^T[d][q] -> AO[q][h*128+d] ----
#pragma unroll
  for (int f = 0; f < 2; ++f) {
    float inv = 1.0f / l[f];
    int q_abs = q0w + f * 16 + l15;
#pragma unroll
    for (int df = 0; df < 8; ++df) {
      uint2 pw;
      pw.x = (unsigned)f2bf(o[f][df][0] * inv) | ((unsigned)f2bf(o[f][df][1] * inv) << 16);
      pw.y = (unsigned)f2bf(o[f][df][2] * inv) | ((unsigned)f2bf(o[f][df][3] * inv) << 16);
      *reinterpret_cast<uint2*>(AO + (size_t)q_abs * QDIM + h * HEAD_DIM + df * 16 + gq * 4) = pw;
    }
  }
}

extern "C" void kernel_launch(void* const* d_in, const int* in_sizes, int n_in,
                              void* d_out, int out_size, void* d_ws, size_t ws_size,
                              hipStream_t stream) {
  const float* hs = (const float*)d_in[0];
  const float* wq = (const float*)d_in[1];
  const float* wk = (const float*)d_in[2];
  const float* wv = (const float*)d_in[3];
  const float* wo = (const float*)d_in[4];
  const float* qnw = (const float*)d_in[5];
  const float* knw = (const float*)d_in[6];
  float* out = (float*)d_out;

  char* base = (char*)d_ws;
  unsigned short* Xb = (unsigned short*)base;                  // 16.78 MB (dead after GEMM1)
  unsigned short* Qb = Xb;                                     // reuse
  unsigned short* Wqkv = (unsigned short*)(base + 16777216);   // 12.58 MB (dead after GEMM1)
  unsigned short* Kb = Wqkv;                                   // reuse (4.19 MB)
  unsigned short* Vtb = (unsigned short*)(base + 16777216 + 4194304);  // reuse (4.19 MB)
  unsigned short* Wob = (unsigned short*)(base + 29360128);    // 8.39 MB (live to end)
  float* QKV = (float*)(base + 37748736);                      // 50.33 MB (dead after norm_rope)
  unsigned short* AOb = (unsigned short*)QKV;                  // reuse (16.78 MB)
  float* cosT = (float*)(base + 88080384);                     // 1 MB
  float* sinT = (float*)(base + 89128960);                     // 1 MB

  int n;
  n = S_LEN * HIDDEN / 4; k_cvt<<<(n + 255) / 256, 256, 0, stream>>>(hs, Xb, n);
  n = QDIM * HIDDEN / 4;  k_cvt<<<(n + 255) / 256, 256, 0, stream>>>(wq, Wqkv, n);
  n = KDIM * HIDDEN / 4;  k_cvt<<<(n + 255) / 256, 256, 0, stream>>>(wk, Wqkv + (size_t)QDIM * HIDDEN, n);
  n = KDIM * HIDDEN / 4;  k_cvt<<<(n + 255) / 256, 256, 0, stream>>>(wv, Wqkv + (size_t)(QDIM + KDIM) * HIDDEN, n);
  n = HIDDEN * QDIM / 4;  k_cvt<<<(n + 255) / 256, 256, 0, stream>>>(wo, Wob, n);
  k_rope_tab<<<(S_LEN * 64) / 256, 256, 0, stream>>>(cosT, sinT);

  k_gemm_bt<<<dim3(QKVD / BN, S_LEN / BM), 256, 0, stream>>>(Xb, Wqkv, QKV, S_LEN, QKVD, HIDDEN);
  k_norm_rope<<<S_LEN, 256, 0, stream>>>(QKV, qnw, knw, cosT, sinT, Qb, Kb, Vtb);
  k_attn<<<dim3(S_LEN / 64, N_KV), 512, 0, stream>>>(Qb, Kb, Vtb, AOb);
  k_gemm_bt<<<dim3(QDIM / BN, S_LEN / BM), 256, 0, stream>>>(AOb, Wob, out, S_LEN, QDIM, HIDDEN);
}